// Round 14
// baseline (388.207 us; speedup 1.0000x reference)
//
#include <hip/hip_runtime.h>
#include <hip/hip_cooperative_groups.h>

namespace cg = cooperative_groups;

#define NN 30000
#define NE 120000
#define TPB 256
#define SB 118   // ceil(NN/256) scan blocks
#define NW 1875  // NN/16 exact
#define CPG 512  // cooperative prep grid (capacity 1024 at 4 blk/CU)

typedef __attribute__((ext_vector_type(8))) __bf16 bf16x8;
typedef __attribute__((ext_vector_type(4))) float f32x4;

union B8 { bf16x8 b; unsigned short u[8]; uint4 q; };

__device__ __forceinline__ float blo(unsigned u) { return __uint_as_float(u << 16); }
__device__ __forceinline__ float bhi(unsigned u) { return __uint_as_float(u & 0xffff0000u); }

__device__ __forceinline__ unsigned short f2b(float f) {
  unsigned u = __float_as_uint(f);
  return (unsigned short)((u + 0x7fff + ((u >> 16) & 1)) >> 16);  // RNE
}

// ---------- weight fragment packing (shared by both prep paths) ----------
__device__ __forceinline__ void pack_wb(int f, const float* kw2, const float* kb2,
                                        const float* root, uint4* Wb) {
  int ct = f >> 6, l = f & 63;
  int j = ct * 16 + (l & 15);
  int k = j >> 5, o = j & 31;
  int i0 = (l >> 4) * 8;
  B8 w;
#pragma unroll
  for (int ii = 0; ii < 8; ii++) {
    int i = i0 + ii;
    float v;
    if (k < 8) v = kw2[k * 1024 + i * 32 + o];
    else if (k == 8) v = kb2[i * 32 + o];
    else v = root[i * 32 + o];
    w.u[ii] = f2b(v);
  }
  Wb[f] = w.q;
}

// ---------- cooperative one-shot prep ----------
struct CPar {
  const float *ea, *kw1, *kb1, *kw2, *kb2, *root;
  const int *src, *dst;
  int *cnt, *rowstart, *wpos, *bsum, *srcs;
  float *icnt, *kcs;
  uint4 *Wb;
};

__global__ __launch_bounds__(TPB, 4) void k_cprep(CPar p) {
  cg::grid_group gg = cg::this_grid();
  __shared__ int S[TPB];
  __shared__ int S2[128];
  const int tid = threadIdx.x;
  const int t = blockIdx.x * TPB + tid;
  // ph0: zero cnt + pack Wb
  if (t < NN) p.cnt[t] = 0;
  if (t < 1280) pack_wb(t, p.kw2, p.kb2, p.root, p.Wb);
  gg.sync();
  // ph1: edge MLP into REGISTERS + degree count
  float ck[8];
  int myd = 0, mys = 0;
  const bool edge = (t < NE);
  if (edge) {
    float a[6];
#pragma unroll
    for (int i = 0; i < 6; i++) a[i] = p.ea[t * 6 + i];
#pragma unroll
    for (int k = 0; k < 8; k++) {
      float s = p.kb1[k];
#pragma unroll
      for (int i = 0; i < 6; i++) s = fmaf(a[i], p.kw1[i * 8 + k], s);
      ck[k] = fmaxf(s, 0.f);
    }
    myd = p.dst[t];
    mys = p.src[t];
    atomicAdd(&p.cnt[myd], 1);
  }
  gg.sync();
  // ph2a: block-level inclusive scan of cnt
  int c = (t < NN) ? p.cnt[t] : 0;
  S[tid] = c;
  __syncthreads();
  for (int off = 1; off < TPB; off <<= 1) {
    int v = S[tid] + ((tid >= off) ? S[tid - off] : 0);
    __syncthreads();
    S[tid] = v;
    __syncthreads();
  }
  int incl = S[tid];
  if (tid == TPB - 1 && blockIdx.x < SB) p.bsum[blockIdx.x] = incl;
  gg.sync();
  // ph2b: block 0 exclusive-scans the block sums
  if (blockIdx.x == 0) {
    if (tid < 128) S2[tid] = (tid < SB) ? p.bsum[tid] : 0;
    __syncthreads();
    for (int off = 1; off < 128; off <<= 1) {
      int v = 0;
      if (tid < 128) v = S2[tid] + ((tid >= off) ? S2[tid - off] : 0);
      __syncthreads();
      if (tid < 128) S2[tid] = v;
      __syncthreads();
    }
    if (tid < SB) p.bsum[tid] = (tid > 0) ? S2[tid - 1] : 0;
  }
  gg.sync();
  // ph2c: rowstart/wpos/icnt
  if (t < NN) {
    int r = p.bsum[blockIdx.x] + incl - c;
    p.rowstart[t] = r;
    p.wpos[t] = r;
    p.icnt[t] = 1.f / (float)max(c, 1);
  }
  gg.sync();
  // ph3: scatter payload from registers
  if (edge) {
    int pos = atomicAdd(&p.wpos[myd], 1);
    p.srcs[pos] = mys;
    float4 a4 = {ck[0], ck[1], ck[2], ck[3]};
    float4 b4 = {ck[4], ck[5], ck[6], ck[7]};
    *(float4*)&p.kcs[(size_t)pos * 8] = a4;
    *(float4*)&p.kcs[(size_t)pos * 8 + 4] = b4;
  }
}

// ---------- fallback prep path (R13-proven) ----------
__global__ void k_init(int* __restrict__ cnt, const float* __restrict__ kw2,
                       const float* __restrict__ kb2, const float* __restrict__ root,
                       uint4* __restrict__ Wb) {
  int bid = blockIdx.x;
  if (bid < SB) {
    int n = bid * TPB + threadIdx.x;
    if (n < NN) cnt[n] = 0;
  } else {
    int f = (bid - SB) * TPB + threadIdx.x;
    if (f < 1280) pack_wb(f, kw2, kb2, root, Wb);
  }
}

__global__ void k_prep(const float* __restrict__ ea, const float* __restrict__ w1,
                       const float* __restrict__ b1, const int* __restrict__ dst,
                       float* __restrict__ kc, int* __restrict__ cnt) {
  int e = blockIdx.x * TPB + threadIdx.x;
  if (e >= NE) return;
  float a[6];
#pragma unroll
  for (int i = 0; i < 6; i++) a[i] = ea[e * 6 + i];
#pragma unroll
  for (int k = 0; k < 8; k++) {
    float s = b1[k];
#pragma unroll
    for (int i = 0; i < 6; i++) s = fmaf(a[i], w1[i * 8 + k], s);
    kc[e * 8 + k] = fmaxf(s, 0.f);
  }
  atomicAdd(&cnt[dst[e]], 1);
}

__global__ void k_scan1(const int* __restrict__ cnt, int* __restrict__ bsum) {
  __shared__ int S[TPB];
  int t = threadIdx.x, n = blockIdx.x * TPB + t;
  S[t] = (n < NN) ? cnt[n] : 0;
  __syncthreads();
  for (int off = TPB / 2; off; off >>= 1) {
    if (t < off) S[t] += S[t + off];
    __syncthreads();
  }
  if (t == 0) bsum[blockIdx.x] = S[0];
}

__global__ void k_scan2(int* __restrict__ bsum) {
  __shared__ int S[128];
  int t = threadIdx.x;
  S[t] = (t < SB) ? bsum[t] : 0;
  __syncthreads();
  for (int off = 1; off < 128; off <<= 1) {
    int v = S[t] + ((t >= off) ? S[t - off] : 0);
    __syncthreads();
    S[t] = v;
    __syncthreads();
  }
  if (t < SB) bsum[t] = (t > 0) ? S[t - 1] : 0;
}

__global__ void k_scan3(const int* __restrict__ cnt, const int* __restrict__ bsum,
                        int* __restrict__ rowstart, int* __restrict__ wpos,
                        float* __restrict__ icnt) {
  __shared__ int S[TPB];
  int t = threadIdx.x, n = blockIdx.x * TPB + t;
  int c = (n < NN) ? cnt[n] : 0;
  S[t] = c;
  __syncthreads();
  for (int off = 1; off < TPB; off <<= 1) {
    int v = S[t] + ((t >= off) ? S[t - off] : 0);
    __syncthreads();
    S[t] = v;
    __syncthreads();
  }
  if (n < NN) {
    int r = bsum[blockIdx.x] + S[t] - c;
    rowstart[n] = r;
    wpos[n] = r;
    icnt[n] = 1.f / (float)max(c, 1);
  }
}

__global__ void k_scatter(const int* __restrict__ dst, const int* __restrict__ src,
                          const float* __restrict__ kc, int* __restrict__ wpos,
                          int* __restrict__ srcs, float* __restrict__ kcs) {
  int e = blockIdx.x * TPB + threadIdx.x;
  if (e >= NE) return;
  int pos = atomicAdd(&wpos[dst[e]], 1);
  srcs[pos] = src[e];
  float4 a = *(const float4*)&kc[e * 8];
  float4 b = *(const float4*)&kc[e * 8 + 4];
  *(float4*)&kcs[(size_t)pos * 8] = a;
  *(float4*)&kcs[(size_t)pos * 8 + 4] = b;
}

// ---------- first MFMA transform (h0 = fc1(x)), R12/R13-proven ----------
__global__ __launch_bounds__(TPB, 4) void k_node1(
    const float* __restrict__ x, const float* __restrict__ fc1w,
    const float* __restrict__ fc1b, const uint4* __restrict__ Wb,
    unsigned* __restrict__ Pb, float* __restrict__ Pr) {
  const int l = threadIdx.x & 63;
  const int wid = blockIdx.x * (TPB / 64) + (threadIdx.x >> 6);
  if (wid >= NW) return;
  const int nb = wid * 16;
  B8 Bf[20];
#pragma unroll
  for (int ct = 0; ct < 20; ct++) Bf[ct].q = Wb[ct * 64 + l];
  const int row = nb + (l & 15);
  const int k0 = (l >> 4) * 8;
  B8 af;
  float xv = x[row];
#pragma unroll
  for (int ii = 0; ii < 8; ii++)
    af.u[ii] = f2b(fmaf(xv, fc1w[k0 + ii], fc1b[k0 + ii]));
  const int oo = l & 15;
  const int r0 = (l >> 4) * 4;
#pragma unroll
  for (int kp = 0; kp < 4; kp++) {
    f32x4 d0 = {0.f, 0.f, 0.f, 0.f}, d1 = d0, d2 = d0, d3 = d0;
    d0 = __builtin_amdgcn_mfma_f32_16x16x32_bf16(af.b, Bf[4 * kp + 0].b, d0, 0, 0, 0);
    d1 = __builtin_amdgcn_mfma_f32_16x16x32_bf16(af.b, Bf[4 * kp + 1].b, d1, 0, 0, 0);
    d2 = __builtin_amdgcn_mfma_f32_16x16x32_bf16(af.b, Bf[4 * kp + 2].b, d2, 0, 0, 0);
    d3 = __builtin_amdgcn_mfma_f32_16x16x32_bf16(af.b, Bf[4 * kp + 3].b, d3, 0, 0, 0);
#pragma unroll
    for (int r = 0; r < 4; r++) {
      int n = nb + r0 + r;
      Pb[(size_t)n * 160 + kp * 32 + oo] = f2b(d0[r]) | ((unsigned)f2b(d2[r]) << 16);
      Pb[(size_t)n * 160 + kp * 32 + 16 + oo] = f2b(d1[r]) | ((unsigned)f2b(d3[r]) << 16);
    }
  }
  {
    f32x4 d0 = {0.f, 0.f, 0.f, 0.f}, d1 = d0, d2 = d0, d3 = d0;
    d0 = __builtin_amdgcn_mfma_f32_16x16x32_bf16(af.b, Bf[16].b, d0, 0, 0, 0);
    d1 = __builtin_amdgcn_mfma_f32_16x16x32_bf16(af.b, Bf[17].b, d1, 0, 0, 0);
    d2 = __builtin_amdgcn_mfma_f32_16x16x32_bf16(af.b, Bf[18].b, d2, 0, 0, 0);
    d3 = __builtin_amdgcn_mfma_f32_16x16x32_bf16(af.b, Bf[19].b, d3, 0, 0, 0);
#pragma unroll
    for (int r = 0; r < 4; r++) {
      int n = nb + r0 + r;
      Pb[(size_t)n * 160 + 128 + oo] = f2b(d0[r]);
      Pb[(size_t)n * 160 + 128 + 16 + oo] = f2b(d1[r]);
      Pr[(size_t)n * 32 + oo] = d2[r];
      Pr[(size_t)n * 32 + 16 + oo] = d3[r];
    }
  }
}

// ---------- fused layer: agg (4 waves x 4 nodes) -> hL -> MFMA transform ----------
__global__ __launch_bounds__(TPB, 4) void k_fused(
    const int* __restrict__ rowstart, const int* __restrict__ cnt,
    const float* __restrict__ icnt, const int* __restrict__ srcs,
    const float* __restrict__ kcs, const unsigned* __restrict__ Pbi,
    const float* __restrict__ Pri, const float* __restrict__ cbias,
    const uint4* __restrict__ Wb, unsigned* __restrict__ Pbo,
    float* __restrict__ Pro) {
  __shared__ float hL[512];
  const int tid = threadIdx.x, w = tid >> 6, lane = tid & 63;
  const int nb = blockIdx.x * 16;
  const int half = lane >> 5, o = lane & 31;
#pragma unroll 1
  for (int q = 0; q < 4; q++) {
    int n = nb + 4 * w + q;
    int rs = rowstart[n], re = rs + cnt[n];
    float acc = 0.f;
    for (int j = rs + half; j < re; j += 2) {
      int s = srcs[j];
      float ckv = (o < 8) ? kcs[(size_t)j * 8 + o] : 0.f;
      const unsigned* Ps = Pbi + (size_t)s * 160;
      unsigned w0 = Ps[o], w1 = Ps[32 + o], w2 = Ps[64 + o], w3 = Ps[96 + o];
      unsigned wb = Ps[128 + o];
      acc += blo(wb);
      acc = fmaf(__shfl(ckv, 0, 32), blo(w0), acc);
      acc = fmaf(__shfl(ckv, 1, 32), bhi(w0), acc);
      acc = fmaf(__shfl(ckv, 2, 32), blo(w1), acc);
      acc = fmaf(__shfl(ckv, 3, 32), bhi(w1), acc);
      acc = fmaf(__shfl(ckv, 4, 32), blo(w2), acc);
      acc = fmaf(__shfl(ckv, 5, 32), bhi(w2), acc);
      acc = fmaf(__shfl(ckv, 6, 32), blo(w3), acc);
      acc = fmaf(__shfl(ckv, 7, 32), bhi(w3), acc);
    }
    acc += __shfl_xor(acc, 32, 64);
    if (lane < 32)
      hL[(4 * w + q) * 32 + o] =
          fmaxf(fmaf(acc, icnt[n], Pri[(size_t)n * 32 + o] + cbias[o]), 0.f);
  }
  __syncthreads();
  // transform: wave w owns kp=w (cts 4w..4w+3) + ct 16+w
  B8 Bf0, Bf1, Bf2, Bf3, Bf4;
  Bf0.q = Wb[(4 * w + 0) * 64 + lane];
  Bf1.q = Wb[(4 * w + 1) * 64 + lane];
  Bf2.q = Wb[(4 * w + 2) * 64 + lane];
  Bf3.q = Wb[(4 * w + 3) * 64 + lane];
  Bf4.q = Wb[(16 + w) * 64 + lane];
  const int row = lane & 15, k0 = (lane >> 4) * 8;
  B8 af;
#pragma unroll
  for (int ii = 0; ii < 8; ii++) af.u[ii] = f2b(hL[row * 32 + k0 + ii]);
  f32x4 z = {0.f, 0.f, 0.f, 0.f};
  f32x4 d0 = __builtin_amdgcn_mfma_f32_16x16x32_bf16(af.b, Bf0.b, z, 0, 0, 0);
  f32x4 d1 = __builtin_amdgcn_mfma_f32_16x16x32_bf16(af.b, Bf1.b, z, 0, 0, 0);
  f32x4 d2 = __builtin_amdgcn_mfma_f32_16x16x32_bf16(af.b, Bf2.b, z, 0, 0, 0);
  f32x4 d3 = __builtin_amdgcn_mfma_f32_16x16x32_bf16(af.b, Bf3.b, z, 0, 0, 0);
  f32x4 d4 = __builtin_amdgcn_mfma_f32_16x16x32_bf16(af.b, Bf4.b, z, 0, 0, 0);
  const int oo = lane & 15, r0 = (lane >> 4) * 4;
#pragma unroll
  for (int r = 0; r < 4; r++) {
    int n = nb + r0 + r;
    Pbo[(size_t)n * 160 + w * 32 + oo] = f2b(d0[r]) | ((unsigned)f2b(d2[r]) << 16);
    Pbo[(size_t)n * 160 + w * 32 + 16 + oo] = f2b(d1[r]) | ((unsigned)f2b(d3[r]) << 16);
    if (w == 0) Pbo[(size_t)n * 160 + 128 + oo] = f2b(d4[r]);
    else if (w == 1) Pbo[(size_t)n * 160 + 128 + 16 + oo] = f2b(d4[r]);
    else if (w == 2) Pro[(size_t)n * 32 + oo] = d4[r];
    else Pro[(size_t)n * 32 + 16 + oo] = d4[r];
  }
}

// ---------- final: aggregate -> h -> fc2 -> out (1 wave/node) ----------
__global__ void k_final(const int* __restrict__ rowstart, const int* __restrict__ cnt,
                        const float* __restrict__ icnt, const int* __restrict__ srcs,
                        const float* __restrict__ kcs, const unsigned* __restrict__ Pb,
                        const float* __restrict__ Pr, const float* __restrict__ cbias,
                        const float* __restrict__ fc2w, const float* __restrict__ fc2b,
                        float* __restrict__ out) {
  int t = blockIdx.x * TPB + threadIdx.x;
  int n = t >> 6;
  if (n >= NN) return;
  int lane = threadIdx.x & 63;
  int half = lane >> 5, o = lane & 31;
  int rs = rowstart[n], re = rs + cnt[n];
  float acc = 0.f;
  for (int j = rs + half; j < re; j += 2) {
    int s = srcs[j];
    float ckv = (o < 8) ? kcs[(size_t)j * 8 + o] : 0.f;
    const unsigned* Ps = Pb + (size_t)s * 160;
    unsigned w0 = Ps[o], w1 = Ps[32 + o], w2 = Ps[64 + o], w3 = Ps[96 + o];
    unsigned wb = Ps[128 + o];
    acc += blo(wb);
    acc = fmaf(__shfl(ckv, 0, 32), blo(w0), acc);
    acc = fmaf(__shfl(ckv, 1, 32), bhi(w0), acc);
    acc = fmaf(__shfl(ckv, 2, 32), blo(w1), acc);
    acc = fmaf(__shfl(ckv, 3, 32), bhi(w1), acc);
    acc = fmaf(__shfl(ckv, 4, 32), blo(w2), acc);
    acc = fmaf(__shfl(ckv, 5, 32), bhi(w2), acc);
    acc = fmaf(__shfl(ckv, 6, 32), blo(w3), acc);
    acc = fmaf(__shfl(ckv, 7, 32), bhi(w3), acc);
  }
  acc += __shfl_xor(acc, 32, 64);
  float hv = fmaxf(fmaf(acc, icnt[n], Pr[(size_t)n * 32 + o] + cbias[o]), 0.f);
  float s2 = hv * fc2w[o];
#pragma unroll
  for (int d = 16; d; d >>= 1) s2 += __shfl_xor(s2, d, 32);
  if (lane == 0) out[n] = s2 + fc2b[0];
}

extern "C" void kernel_launch(void* const* d_in, const int* in_sizes, int n_in,
                              void* d_out, int out_size, void* d_ws, size_t ws_size,
                              hipStream_t stream) {
  const float* x     = (const float*)d_in[0];
  const int*   ei    = (const int*)d_in[1];
  const float* ea    = (const float*)d_in[2];
  const float* fc1w  = (const float*)d_in[3];
  const float* fc1b  = (const float*)d_in[4];
  const float* kw1   = (const float*)d_in[5];
  const float* kb1   = (const float*)d_in[6];
  const float* kw2   = (const float*)d_in[7];
  const float* kb2   = (const float*)d_in[8];
  const float* root  = (const float*)d_in[9];
  const float* cbias = (const float*)d_in[10];
  const float* fc2w  = (const float*)d_in[11];
  const float* fc2b  = (const float*)d_in[12];
  float* out = (float*)d_out;
  const int* srcp = ei;
  const int* dstp = ei + NE;

  float* ws = (float*)d_ws;
  float* kc       = ws;                        // NE*8 (fallback path only)
  float* kcs      = kc + NE * 8;               // NE*8
  int*   srcs     = (int*)(kcs + NE * 8);      // NE
  float* icnt     = (float*)(srcs + NE);       // NN
  float* Pr0      = icnt + NN;                 // NN*32
  float* Pr1      = Pr0 + NN * 32;             // NN*32
  int*   cnt      = (int*)(Pr1 + NN * 32);     // NN
  int*   rowstart = cnt + NN;                  // NN
  int*   wpos     = rowstart + NN;             // NN
  int*   bsum     = wpos + NN;                 // 128
  uint4* Wb       = (uint4*)(bsum + 128);      // 1280 uint4
  unsigned* Pb0   = (unsigned*)(Wb + 1280);    // NN*160
  unsigned* Pb1   = Pb0 + (size_t)NN * 160;    // NN*160

  CPar cp;
  cp.ea = ea; cp.kw1 = kw1; cp.kb1 = kb1; cp.kw2 = kw2; cp.kb2 = kb2; cp.root = root;
  cp.src = srcp; cp.dst = dstp;
  cp.cnt = cnt; cp.rowstart = rowstart; cp.wpos = wpos; cp.bsum = bsum;
  cp.srcs = srcs; cp.icnt = icnt; cp.kcs = kcs; cp.Wb = Wb;
  void* cargs[] = {&cp};
  hipError_t ce = hipLaunchCooperativeKernel((const void*)k_cprep, dim3(CPG),
                                             dim3(TPB), cargs, 0, stream);
  if (ce != hipSuccess) {
    (void)hipGetLastError();  // clear; use the proven classic prep chain
    k_init<<<SB + 5, TPB, 0, stream>>>(cnt, kw2, kb2, root, Wb);
    k_prep<<<(NE + TPB - 1) / TPB, TPB, 0, stream>>>(ea, kw1, kb1, dstp, kc, cnt);
    k_scan1<<<SB, TPB, 0, stream>>>(cnt, bsum);
    k_scan2<<<1, 128, 0, stream>>>(bsum);
    k_scan3<<<SB, TPB, 0, stream>>>(cnt, bsum, rowstart, wpos, icnt);
    k_scatter<<<(NE + TPB - 1) / TPB, TPB, 0, stream>>>(dstp, srcp, kc, wpos, srcs, kcs);
  }

  k_node1<<<(NW * 64 + TPB - 1) / TPB, TPB, 0, stream>>>(x, fc1w, fc1b, Wb, Pb0, Pr0);
  k_fused<<<NW, TPB, 0, stream>>>(rowstart, cnt, icnt, srcs, kcs, Pb0, Pr0, cbias,
                                  Wb, Pb1, Pr1);
  k_fused<<<NW, TPB, 0, stream>>>(rowstart, cnt, icnt, srcs, kcs, Pb1, Pr1, cbias,
                                  Wb, Pb0, Pr0);
  k_fused<<<NW, TPB, 0, stream>>>(rowstart, cnt, icnt, srcs, kcs, Pb0, Pr0, cbias,
                                  Wb, Pb1, Pr1);
  k_final<<<(NN * 64 + TPB - 1) / TPB, TPB, 0, stream>>>(
      rowstart, cnt, icnt, srcs, kcs, Pb1, Pr1, cbias, fc2w, fc2b, out);
}

// Round 15
// 120.788 us; speedup vs baseline: 3.2140x; 3.2140x over previous
//
#include <hip/hip_runtime.h>

#define NN 30000
#define NE 120000
#define TPB 256
#define SB 118   // ceil(NN/256) scan blocks
#define NW 1875  // NN/16 exact

typedef __attribute__((ext_vector_type(8))) __bf16 bf16x8;
typedef __attribute__((ext_vector_type(4))) float f32x4;

union B8 { bf16x8 b; unsigned short u[8]; uint4 q; };

__device__ __forceinline__ float blo(unsigned u) { return __uint_as_float(u << 16); }
__device__ __forceinline__ float bhi(unsigned u) { return __uint_as_float(u & 0xffff0000u); }

__device__ __forceinline__ unsigned short f2b(float f) {
  unsigned u = __float_as_uint(f);
  return (unsigned short)((u + 0x7fff + ((u >> 16) & 1)) >> 16);  // RNE
}

// ---------- weight fragment packing ----------
__device__ __forceinline__ void pack_wb(int f, const float* kw2, const float* kb2,
                                        const float* root, uint4* Wb) {
  int ct = f >> 6, l = f & 63;
  int j = ct * 16 + (l & 15);
  int k = j >> 5, o = j & 31;
  int i0 = (l >> 4) * 8;
  B8 w;
#pragma unroll
  for (int ii = 0; ii < 8; ii++) {
    int i = i0 + ii;
    float v;
    if (k < 8) v = kw2[k * 1024 + i * 32 + o];
    else if (k == 8) v = kb2[i * 32 + o];
    else v = root[i * 32 + o];
    w.u[ii] = f2b(v);
  }
  Wb[f] = w.q;
}

// ---------- classic prep chain (R13-proven) ----------
__global__ void k_init(int* __restrict__ cnt, const float* __restrict__ kw2,
                       const float* __restrict__ kb2, const float* __restrict__ root,
                       uint4* __restrict__ Wb) {
  int bid = blockIdx.x;
  if (bid < SB) {
    int n = bid * TPB + threadIdx.x;
    if (n < NN) cnt[n] = 0;
  } else {
    int f = (bid - SB) * TPB + threadIdx.x;
    if (f < 1280) pack_wb(f, kw2, kb2, root, Wb);
  }
}

__global__ void k_prep(const float* __restrict__ ea, const float* __restrict__ w1,
                       const float* __restrict__ b1, const int* __restrict__ dst,
                       float* __restrict__ kc, int* __restrict__ cnt) {
  int e = blockIdx.x * TPB + threadIdx.x;
  if (e >= NE) return;
  float a[6];
#pragma unroll
  for (int i = 0; i < 6; i++) a[i] = ea[e * 6 + i];
#pragma unroll
  for (int k = 0; k < 8; k++) {
    float s = b1[k];
#pragma unroll
    for (int i = 0; i < 6; i++) s = fmaf(a[i], w1[i * 8 + k], s);
    kc[e * 8 + k] = fmaxf(s, 0.f);
  }
  atomicAdd(&cnt[dst[e]], 1);
}

__global__ void k_scan1(const int* __restrict__ cnt, int* __restrict__ bsum) {
  __shared__ int S[TPB];
  int t = threadIdx.x, n = blockIdx.x * TPB + t;
  S[t] = (n < NN) ? cnt[n] : 0;
  __syncthreads();
  for (int off = TPB / 2; off; off >>= 1) {
    if (t < off) S[t] += S[t + off];
    __syncthreads();
  }
  if (t == 0) bsum[blockIdx.x] = S[0];
}

__global__ void k_scan2(int* __restrict__ bsum) {
  __shared__ int S[128];
  int t = threadIdx.x;
  S[t] = (t < SB) ? bsum[t] : 0;
  __syncthreads();
  for (int off = 1; off < 128; off <<= 1) {
    int v = S[t] + ((t >= off) ? S[t - off] : 0);
    __syncthreads();
    S[t] = v;
    __syncthreads();
  }
  if (t < SB) bsum[t] = (t > 0) ? S[t - 1] : 0;
}

__global__ void k_scan3(const int* __restrict__ cnt, const int* __restrict__ bsum,
                        int* __restrict__ rowstart, int* __restrict__ wpos,
                        float* __restrict__ icnt) {
  __shared__ int S[TPB];
  int t = threadIdx.x, n = blockIdx.x * TPB + t;
  int c = (n < NN) ? cnt[n] : 0;
  S[t] = c;
  __syncthreads();
  for (int off = 1; off < TPB; off <<= 1) {
    int v = S[t] + ((t >= off) ? S[t - off] : 0);
    __syncthreads();
    S[t] = v;
    __syncthreads();
  }
  if (n < NN) {
    int r = bsum[blockIdx.x] + S[t] - c;
    rowstart[n] = r;
    wpos[n] = r;
    icnt[n] = 1.f / (float)max(c, 1);
  }
}

__global__ void k_scatter(const int* __restrict__ dst, const int* __restrict__ src,
                          const float* __restrict__ kc, int* __restrict__ wpos,
                          int* __restrict__ srcs, float* __restrict__ kcs) {
  int e = blockIdx.x * TPB + threadIdx.x;
  if (e >= NE) return;
  int pos = atomicAdd(&wpos[dst[e]], 1);
  srcs[pos] = src[e];
  float4 a = *(const float4*)&kc[e * 8];
  float4 b = *(const float4*)&kc[e * 8 + 4];
  *(float4*)&kcs[(size_t)pos * 8] = a;
  *(float4*)&kcs[(size_t)pos * 8 + 4] = b;
}

// ---------- first MFMA transform (h0 = fc1(x)), R12/R13-proven ----------
__global__ __launch_bounds__(TPB, 4) void k_node1(
    const float* __restrict__ x, const float* __restrict__ fc1w,
    const float* __restrict__ fc1b, const uint4* __restrict__ Wb,
    unsigned* __restrict__ Pb, float* __restrict__ Pr) {
  const int l = threadIdx.x & 63;
  const int wid = blockIdx.x * (TPB / 64) + (threadIdx.x >> 6);
  if (wid >= NW) return;
  const int nb = wid * 16;
  B8 Bf[20];
#pragma unroll
  for (int ct = 0; ct < 20; ct++) Bf[ct].q = Wb[ct * 64 + l];
  const int row = nb + (l & 15);
  const int k0 = (l >> 4) * 8;
  B8 af;
  float xv = x[row];
#pragma unroll
  for (int ii = 0; ii < 8; ii++)
    af.u[ii] = f2b(fmaf(xv, fc1w[k0 + ii], fc1b[k0 + ii]));
  const int oo = l & 15;
  const int r0 = (l >> 4) * 4;
#pragma unroll
  for (int kp = 0; kp < 4; kp++) {
    f32x4 d0 = {0.f, 0.f, 0.f, 0.f}, d1 = d0, d2 = d0, d3 = d0;
    d0 = __builtin_amdgcn_mfma_f32_16x16x32_bf16(af.b, Bf[4 * kp + 0].b, d0, 0, 0, 0);
    d1 = __builtin_amdgcn_mfma_f32_16x16x32_bf16(af.b, Bf[4 * kp + 1].b, d1, 0, 0, 0);
    d2 = __builtin_amdgcn_mfma_f32_16x16x32_bf16(af.b, Bf[4 * kp + 2].b, d2, 0, 0, 0);
    d3 = __builtin_amdgcn_mfma_f32_16x16x32_bf16(af.b, Bf[4 * kp + 3].b, d3, 0, 0, 0);
#pragma unroll
    for (int r = 0; r < 4; r++) {
      int n = nb + r0 + r;
      Pb[(size_t)n * 160 + kp * 32 + oo] = f2b(d0[r]) | ((unsigned)f2b(d2[r]) << 16);
      Pb[(size_t)n * 160 + kp * 32 + 16 + oo] = f2b(d1[r]) | ((unsigned)f2b(d3[r]) << 16);
    }
  }
  {
    f32x4 d0 = {0.f, 0.f, 0.f, 0.f}, d1 = d0, d2 = d0, d3 = d0;
    d0 = __builtin_amdgcn_mfma_f32_16x16x32_bf16(af.b, Bf[16].b, d0, 0, 0, 0);
    d1 = __builtin_amdgcn_mfma_f32_16x16x32_bf16(af.b, Bf[17].b, d1, 0, 0, 0);
    d2 = __builtin_amdgcn_mfma_f32_16x16x32_bf16(af.b, Bf[18].b, d2, 0, 0, 0);
    d3 = __builtin_amdgcn_mfma_f32_16x16x32_bf16(af.b, Bf[19].b, d3, 0, 0, 0);
#pragma unroll
    for (int r = 0; r < 4; r++) {
      int n = nb + r0 + r;
      Pb[(size_t)n * 160 + 128 + oo] = f2b(d0[r]);
      Pb[(size_t)n * 160 + 128 + 16 + oo] = f2b(d1[r]);
      Pr[(size_t)n * 32 + oo] = d2[r];
      Pr[(size_t)n * 32 + 16 + oo] = d3[r];
    }
  }
}

// ---------- fused layer: agg (4 waves x 4 nodes) -> hL -> MFMA transform ----------
// R14-verified: 28 VGPR, no spill, FETCH ~38MB / WRITE ~22.5MB per launch.
__global__ __launch_bounds__(TPB, 4) void k_fused(
    const int* __restrict__ rowstart, const int* __restrict__ cnt,
    const float* __restrict__ icnt, const int* __restrict__ srcs,
    const float* __restrict__ kcs, const unsigned* __restrict__ Pbi,
    const float* __restrict__ Pri, const float* __restrict__ cbias,
    const uint4* __restrict__ Wb, unsigned* __restrict__ Pbo,
    float* __restrict__ Pro) {
  __shared__ float hL[512];
  const int tid = threadIdx.x, w = tid >> 6, lane = tid & 63;
  const int nb = blockIdx.x * 16;
  const int half = lane >> 5, o = lane & 31;
#pragma unroll 1
  for (int q = 0; q < 4; q++) {
    int n = nb + 4 * w + q;
    int rs = rowstart[n], re = rs + cnt[n];
    float acc = 0.f;
    for (int j = rs + half; j < re; j += 2) {
      int s = srcs[j];
      float ckv = (o < 8) ? kcs[(size_t)j * 8 + o] : 0.f;
      const unsigned* Ps = Pbi + (size_t)s * 160;
      unsigned w0 = Ps[o], w1 = Ps[32 + o], w2 = Ps[64 + o], w3 = Ps[96 + o];
      unsigned wb = Ps[128 + o];
      acc += blo(wb);
      acc = fmaf(__shfl(ckv, 0, 32), blo(w0), acc);
      acc = fmaf(__shfl(ckv, 1, 32), bhi(w0), acc);
      acc = fmaf(__shfl(ckv, 2, 32), blo(w1), acc);
      acc = fmaf(__shfl(ckv, 3, 32), bhi(w1), acc);
      acc = fmaf(__shfl(ckv, 4, 32), blo(w2), acc);
      acc = fmaf(__shfl(ckv, 5, 32), bhi(w2), acc);
      acc = fmaf(__shfl(ckv, 6, 32), blo(w3), acc);
      acc = fmaf(__shfl(ckv, 7, 32), bhi(w3), acc);
    }
    acc += __shfl_xor(acc, 32, 64);
    if (lane < 32)
      hL[(4 * w + q) * 32 + o] =
          fmaxf(fmaf(acc, icnt[n], Pri[(size_t)n * 32 + o] + cbias[o]), 0.f);
  }
  __syncthreads();
  // transform: wave w owns kp=w (cts 4w..4w+3) + ct 16+w
  B8 Bf0, Bf1, Bf2, Bf3, Bf4;
  Bf0.q = Wb[(4 * w + 0) * 64 + lane];
  Bf1.q = Wb[(4 * w + 1) * 64 + lane];
  Bf2.q = Wb[(4 * w + 2) * 64 + lane];
  Bf3.q = Wb[(4 * w + 3) * 64 + lane];
  Bf4.q = Wb[(16 + w) * 64 + lane];
  const int row = lane & 15, k0 = (lane >> 4) * 8;
  B8 af;
#pragma unroll
  for (int ii = 0; ii < 8; ii++) af.u[ii] = f2b(hL[row * 32 + k0 + ii]);
  f32x4 z = {0.f, 0.f, 0.f, 0.f};
  f32x4 d0 = __builtin_amdgcn_mfma_f32_16x16x32_bf16(af.b, Bf0.b, z, 0, 0, 0);
  f32x4 d1 = __builtin_amdgcn_mfma_f32_16x16x32_bf16(af.b, Bf1.b, z, 0, 0, 0);
  f32x4 d2 = __builtin_amdgcn_mfma_f32_16x16x32_bf16(af.b, Bf2.b, z, 0, 0, 0);
  f32x4 d3 = __builtin_amdgcn_mfma_f32_16x16x32_bf16(af.b, Bf3.b, z, 0, 0, 0);
  f32x4 d4 = __builtin_amdgcn_mfma_f32_16x16x32_bf16(af.b, Bf4.b, z, 0, 0, 0);
  const int oo = lane & 15, r0 = (lane >> 4) * 4;
#pragma unroll
  for (int r = 0; r < 4; r++) {
    int n = nb + r0 + r;
    Pbo[(size_t)n * 160 + w * 32 + oo] = f2b(d0[r]) | ((unsigned)f2b(d2[r]) << 16);
    Pbo[(size_t)n * 160 + w * 32 + 16 + oo] = f2b(d1[r]) | ((unsigned)f2b(d3[r]) << 16);
    if (w == 0) Pbo[(size_t)n * 160 + 128 + oo] = f2b(d4[r]);
    else if (w == 1) Pbo[(size_t)n * 160 + 128 + 16 + oo] = f2b(d4[r]);
    else if (w == 2) Pro[(size_t)n * 32 + oo] = d4[r];
    else Pro[(size_t)n * 32 + 16 + oo] = d4[r];
  }
}

// ---------- final: aggregate -> h -> fc2 -> out (1 wave/node) ----------
__global__ void k_final(const int* __restrict__ rowstart, const int* __restrict__ cnt,
                        const float* __restrict__ icnt, const int* __restrict__ srcs,
                        const float* __restrict__ kcs, const unsigned* __restrict__ Pb,
                        const float* __restrict__ Pr, const float* __restrict__ cbias,
                        const float* __restrict__ fc2w, const float* __restrict__ fc2b,
                        float* __restrict__ out) {
  int t = blockIdx.x * TPB + threadIdx.x;
  int n = t >> 6;
  if (n >= NN) return;
  int lane = threadIdx.x & 63;
  int half = lane >> 5, o = lane & 31;
  int rs = rowstart[n], re = rs + cnt[n];
  float acc = 0.f;
  for (int j = rs + half; j < re; j += 2) {
    int s = srcs[j];
    float ckv = (o < 8) ? kcs[(size_t)j * 8 + o] : 0.f;
    const unsigned* Ps = Pb + (size_t)s * 160;
    unsigned w0 = Ps[o], w1 = Ps[32 + o], w2 = Ps[64 + o], w3 = Ps[96 + o];
    unsigned wb = Ps[128 + o];
    acc += blo(wb);
    acc = fmaf(__shfl(ckv, 0, 32), blo(w0), acc);
    acc = fmaf(__shfl(ckv, 1, 32), bhi(w0), acc);
    acc = fmaf(__shfl(ckv, 2, 32), blo(w1), acc);
    acc = fmaf(__shfl(ckv, 3, 32), bhi(w1), acc);
    acc = fmaf(__shfl(ckv, 4, 32), blo(w2), acc);
    acc = fmaf(__shfl(ckv, 5, 32), bhi(w2), acc);
    acc = fmaf(__shfl(ckv, 6, 32), blo(w3), acc);
    acc = fmaf(__shfl(ckv, 7, 32), bhi(w3), acc);
  }
  acc += __shfl_xor(acc, 32, 64);
  float hv = fmaxf(fmaf(acc, icnt[n], Pr[(size_t)n * 32 + o] + cbias[o]), 0.f);
  float s2 = hv * fc2w[o];
#pragma unroll
  for (int d = 16; d; d >>= 1) s2 += __shfl_xor(s2, d, 32);
  if (lane == 0) out[n] = s2 + fc2b[0];
}

extern "C" void kernel_launch(void* const* d_in, const int* in_sizes, int n_in,
                              void* d_out, int out_size, void* d_ws, size_t ws_size,
                              hipStream_t stream) {
  const float* x     = (const float*)d_in[0];
  const int*   ei    = (const int*)d_in[1];
  const float* ea    = (const float*)d_in[2];
  const float* fc1w  = (const float*)d_in[3];
  const float* fc1b  = (const float*)d_in[4];
  const float* kw1   = (const float*)d_in[5];
  const float* kb1   = (const float*)d_in[6];
  const float* kw2   = (const float*)d_in[7];
  const float* kb2   = (const float*)d_in[8];
  const float* root  = (const float*)d_in[9];
  const float* cbias = (const float*)d_in[10];
  const float* fc2w  = (const float*)d_in[11];
  const float* fc2b  = (const float*)d_in[12];
  float* out = (float*)d_out;
  const int* srcp = ei;
  const int* dstp = ei + NE;

  float* ws = (float*)d_ws;
  float* kc       = ws;                        // NE*8
  float* kcs      = kc + NE * 8;               // NE*8
  int*   srcs     = (int*)(kcs + NE * 8);      // NE
  float* icnt     = (float*)(srcs + NE);       // NN
  float* Pr0      = icnt + NN;                 // NN*32
  float* Pr1      = Pr0 + NN * 32;             // NN*32
  int*   cnt      = (int*)(Pr1 + NN * 32);     // NN
  int*   rowstart = cnt + NN;                  // NN
  int*   wpos     = rowstart + NN;             // NN
  int*   bsum     = wpos + NN;                 // 128
  uint4* Wb       = (uint4*)(bsum + 128);      // 1280 uint4
  unsigned* Pb0   = (unsigned*)(Wb + 1280);    // NN*160
  unsigned* Pb1   = Pb0 + (size_t)NN * 160;    // NN*160

  k_init<<<SB + 5, TPB, 0, stream>>>(cnt, kw2, kb2, root, Wb);
  k_prep<<<(NE + TPB - 1) / TPB, TPB, 0, stream>>>(ea, kw1, kb1, dstp, kc, cnt);
  k_scan1<<<SB, TPB, 0, stream>>>(cnt, bsum);
  k_scan2<<<1, 128, 0, stream>>>(bsum);
  k_scan3<<<SB, TPB, 0, stream>>>(cnt, bsum, rowstart, wpos, icnt);
  k_scatter<<<(NE + TPB - 1) / TPB, TPB, 0, stream>>>(dstp, srcp, kc, wpos, srcs, kcs);

  k_node1<<<(NW * 64 + TPB - 1) / TPB, TPB, 0, stream>>>(x, fc1w, fc1b, Wb, Pb0, Pr0);
  k_fused<<<NW, TPB, 0, stream>>>(rowstart, cnt, icnt, srcs, kcs, Pb0, Pr0, cbias,
                                  Wb, Pb1, Pr1);
  k_fused<<<NW, TPB, 0, stream>>>(rowstart, cnt, icnt, srcs, kcs, Pb1, Pr1, cbias,
                                  Wb, Pb0, Pr0);
  k_fused<<<NW, TPB, 0, stream>>>(rowstart, cnt, icnt, srcs, kcs, Pb0, Pr0, cbias,
                                  Wb, Pb1, Pr1);
  k_final<<<(NN * 64 + TPB - 1) / TPB, TPB, 0, stream>>>(
      rowstart, cnt, icnt, srcs, kcs, Pb1, Pr1, cbias, fc2w, fc2b, out);
}

// Round 16
// 119.425 us; speedup vs baseline: 3.2506x; 1.0114x over previous
//
#include <hip/hip_runtime.h>

#define NN 30000
#define NE 120000
#define TPB 256
#define SB 118   // ceil(NN/256)
#define NW 1875  // NN/16 exact
#define NB1 469  // ceil(NW*64/256) blocks for node1 part

typedef __attribute__((ext_vector_type(8))) __bf16 bf16x8;
typedef __attribute__((ext_vector_type(4))) float f32x4;

union B8 { bf16x8 b; unsigned short u[8]; uint4 q; };

__device__ __forceinline__ float blo(unsigned u) { return __uint_as_float(u << 16); }
__device__ __forceinline__ float bhi(unsigned u) { return __uint_as_float(u & 0xffff0000u); }

__device__ __forceinline__ unsigned short f2b(float f) {
  unsigned u = __float_as_uint(f);
  return (unsigned short)((u + 0x7fff + ((u >> 16) & 1)) >> 16);  // RNE
}

// ---------- weight fragment packing ----------
__device__ __forceinline__ void pack_wb(int f, const float* kw2, const float* kb2,
                                        const float* root, uint4* Wb) {
  int ct = f >> 6, l = f & 63;
  int j = ct * 16 + (l & 15);
  int k = j >> 5, o = j & 31;
  int i0 = (l >> 4) * 8;
  B8 w;
#pragma unroll
  for (int ii = 0; ii < 8; ii++) {
    int i = i0 + ii;
    float v;
    if (k < 8) v = kw2[k * 1024 + i * 32 + o];
    else if (k == 8) v = kb2[i * 32 + o];
    else v = root[i * 32 + o];
    w.u[ii] = f2b(v);
  }
  Wb[f] = w.q;
}

// zero cnt + gtotal, pack Wb
__global__ void k_init(int* __restrict__ cnt, int* __restrict__ gtotal,
                       const float* __restrict__ kw2, const float* __restrict__ kb2,
                       const float* __restrict__ root, uint4* __restrict__ Wb) {
  int bid = blockIdx.x;
  if (bid < SB) {
    int n = bid * TPB + threadIdx.x;
    if (n < NN) cnt[n] = 0;
    if (bid == 0 && threadIdx.x == 0) *gtotal = 0;
  } else {
    int f = (bid - SB) * TPB + threadIdx.x;
    if (f < 1280) pack_wb(f, kw2, kb2, root, Wb);
  }
}

// edge MLP -> kc; degree count
__global__ void k_prep(const float* __restrict__ ea, const float* __restrict__ w1,
                       const float* __restrict__ b1, const int* __restrict__ dst,
                       float* __restrict__ kc, int* __restrict__ cnt) {
  int e = blockIdx.x * TPB + threadIdx.x;
  if (e >= NE) return;
  float a[6];
#pragma unroll
  for (int i = 0; i < 6; i++) a[i] = ea[e * 6 + i];
#pragma unroll
  for (int k = 0; k < 8; k++) {
    float s = b1[k];
#pragma unroll
    for (int i = 0; i < 6; i++) s = fmaf(a[i], w1[i * 8 + k], s);
    kc[e * 8 + k] = fmaxf(s, 0.f);
  }
  atomicAdd(&cnt[dst[e]], 1);
}

// CSR range allocation WITHOUT prefix scan: inter-node order is irrelevant,
// only per-node contiguity matters. Wave-level atomic (compiler DPP-scans).
__global__ void k_alloc(const int* __restrict__ cnt, int* __restrict__ gtotal,
                        int* __restrict__ rowstart, int* __restrict__ wpos,
                        float* __restrict__ icnt) {
  int n = blockIdx.x * TPB + threadIdx.x;
  if (n >= NN) return;
  int c = cnt[n];
  int r = atomicAdd(gtotal, c);
  rowstart[n] = r;
  wpos[n] = r;
  icnt[n] = 1.f / (float)max(c, 1);
}

// fused: blocks [0,NB1) = first MFMA transform (h0=fc1(x)); blocks [NB1,..) = scatter
__global__ __launch_bounds__(TPB, 4) void k_scatnode(
    const int* __restrict__ dst, const int* __restrict__ src,
    const float* __restrict__ kc, int* __restrict__ wpos, int* __restrict__ srcs,
    float* __restrict__ kcs, const float* __restrict__ x,
    const float* __restrict__ fc1w, const float* __restrict__ fc1b,
    const uint4* __restrict__ Wb, unsigned* __restrict__ Pb, float* __restrict__ Pr) {
  if (blockIdx.x < NB1) {
    const int l = threadIdx.x & 63;
    const int wid = blockIdx.x * (TPB / 64) + (threadIdx.x >> 6);
    if (wid >= NW) return;
    const int nb = wid * 16;
    B8 Bf[20];
#pragma unroll
    for (int ct = 0; ct < 20; ct++) Bf[ct].q = Wb[ct * 64 + l];
    const int row = nb + (l & 15);
    const int k0 = (l >> 4) * 8;
    B8 af;
    float xv = x[row];
#pragma unroll
    for (int ii = 0; ii < 8; ii++)
      af.u[ii] = f2b(fmaf(xv, fc1w[k0 + ii], fc1b[k0 + ii]));
    const int oo = l & 15;
    const int r0 = (l >> 4) * 4;
#pragma unroll
    for (int kp = 0; kp < 4; kp++) {
      f32x4 d0 = {0.f, 0.f, 0.f, 0.f}, d1 = d0, d2 = d0, d3 = d0;
      d0 = __builtin_amdgcn_mfma_f32_16x16x32_bf16(af.b, Bf[4 * kp + 0].b, d0, 0, 0, 0);
      d1 = __builtin_amdgcn_mfma_f32_16x16x32_bf16(af.b, Bf[4 * kp + 1].b, d1, 0, 0, 0);
      d2 = __builtin_amdgcn_mfma_f32_16x16x32_bf16(af.b, Bf[4 * kp + 2].b, d2, 0, 0, 0);
      d3 = __builtin_amdgcn_mfma_f32_16x16x32_bf16(af.b, Bf[4 * kp + 3].b, d3, 0, 0, 0);
#pragma unroll
      for (int r = 0; r < 4; r++) {
        int n = nb + r0 + r;
        Pb[(size_t)n * 160 + kp * 32 + oo] = f2b(d0[r]) | ((unsigned)f2b(d2[r]) << 16);
        Pb[(size_t)n * 160 + kp * 32 + 16 + oo] = f2b(d1[r]) | ((unsigned)f2b(d3[r]) << 16);
      }
    }
    {
      f32x4 d0 = {0.f, 0.f, 0.f, 0.f}, d1 = d0, d2 = d0, d3 = d0;
      d0 = __builtin_amdgcn_mfma_f32_16x16x32_bf16(af.b, Bf[16].b, d0, 0, 0, 0);
      d1 = __builtin_amdgcn_mfma_f32_16x16x32_bf16(af.b, Bf[17].b, d1, 0, 0, 0);
      d2 = __builtin_amdgcn_mfma_f32_16x16x32_bf16(af.b, Bf[18].b, d2, 0, 0, 0);
      d3 = __builtin_amdgcn_mfma_f32_16x16x32_bf16(af.b, Bf[19].b, d3, 0, 0, 0);
#pragma unroll
      for (int r = 0; r < 4; r++) {
        int n = nb + r0 + r;
        Pb[(size_t)n * 160 + 128 + oo] = f2b(d0[r]);
        Pb[(size_t)n * 160 + 128 + 16 + oo] = f2b(d1[r]);
        Pr[(size_t)n * 32 + oo] = d2[r];
        Pr[(size_t)n * 32 + 16 + oo] = d3[r];
      }
    }
  } else {
    int e = (blockIdx.x - NB1) * TPB + threadIdx.x;
    if (e >= NE) return;
    int pos = atomicAdd(&wpos[dst[e]], 1);
    srcs[pos] = src[e];
    float4 a = *(const float4*)&kc[e * 8];
    float4 b = *(const float4*)&kc[e * 8 + 4];
    *(float4*)&kcs[(size_t)pos * 8] = a;
    *(float4*)&kcs[(size_t)pos * 8 + 4] = b;
  }
}

// ---------- fused layer: agg (4 waves x 4 nodes) -> hL -> MFMA transform ----------
__global__ __launch_bounds__(TPB, 4) void k_fused(
    const int* __restrict__ rowstart, const int* __restrict__ cnt,
    const float* __restrict__ icnt, const int* __restrict__ srcs,
    const float* __restrict__ kcs, const unsigned* __restrict__ Pbi,
    const float* __restrict__ Pri, const float* __restrict__ cbias,
    const uint4* __restrict__ Wb, unsigned* __restrict__ Pbo,
    float* __restrict__ Pro) {
  __shared__ float hL[512];
  const int tid = threadIdx.x, w = tid >> 6, lane = tid & 63;
  const int nb = blockIdx.x * 16;
  const int half = lane >> 5, o = lane & 31;
#pragma unroll 1
  for (int q = 0; q < 4; q++) {
    int n = nb + 4 * w + q;
    int rs = rowstart[n], re = rs + cnt[n];
    float acc = 0.f;
    for (int j = rs + half; j < re; j += 2) {
      int s = srcs[j];
      float ckv = (o < 8) ? kcs[(size_t)j * 8 + o] : 0.f;
      const unsigned* Ps = Pbi + (size_t)s * 160;
      unsigned w0 = Ps[o], w1 = Ps[32 + o], w2 = Ps[64 + o], w3 = Ps[96 + o];
      unsigned wb = Ps[128 + o];
      acc += blo(wb);
      acc = fmaf(__shfl(ckv, 0, 32), blo(w0), acc);
      acc = fmaf(__shfl(ckv, 1, 32), bhi(w0), acc);
      acc = fmaf(__shfl(ckv, 2, 32), blo(w1), acc);
      acc = fmaf(__shfl(ckv, 3, 32), bhi(w1), acc);
      acc = fmaf(__shfl(ckv, 4, 32), blo(w2), acc);
      acc = fmaf(__shfl(ckv, 5, 32), bhi(w2), acc);
      acc = fmaf(__shfl(ckv, 6, 32), blo(w3), acc);
      acc = fmaf(__shfl(ckv, 7, 32), bhi(w3), acc);
    }
    acc += __shfl_xor(acc, 32, 64);
    if (lane < 32)
      hL[(4 * w + q) * 32 + o] =
          fmaxf(fmaf(acc, icnt[n], Pri[(size_t)n * 32 + o] + cbias[o]), 0.f);
  }
  __syncthreads();
  B8 Bf0, Bf1, Bf2, Bf3, Bf4;
  Bf0.q = Wb[(4 * w + 0) * 64 + lane];
  Bf1.q = Wb[(4 * w + 1) * 64 + lane];
  Bf2.q = Wb[(4 * w + 2) * 64 + lane];
  Bf3.q = Wb[(4 * w + 3) * 64 + lane];
  Bf4.q = Wb[(16 + w) * 64 + lane];
  const int row = lane & 15, k0 = (lane >> 4) * 8;
  B8 af;
#pragma unroll
  for (int ii = 0; ii < 8; ii++) af.u[ii] = f2b(hL[row * 32 + k0 + ii]);
  f32x4 z = {0.f, 0.f, 0.f, 0.f};
  f32x4 d0 = __builtin_amdgcn_mfma_f32_16x16x32_bf16(af.b, Bf0.b, z, 0, 0, 0);
  f32x4 d1 = __builtin_amdgcn_mfma_f32_16x16x32_bf16(af.b, Bf1.b, z, 0, 0, 0);
  f32x4 d2 = __builtin_amdgcn_mfma_f32_16x16x32_bf16(af.b, Bf2.b, z, 0, 0, 0);
  f32x4 d3 = __builtin_amdgcn_mfma_f32_16x16x32_bf16(af.b, Bf3.b, z, 0, 0, 0);
  f32x4 d4 = __builtin_amdgcn_mfma_f32_16x16x32_bf16(af.b, Bf4.b, z, 0, 0, 0);
  const int oo = lane & 15, r0 = (lane >> 4) * 4;
#pragma unroll
  for (int r = 0; r < 4; r++) {
    int n = nb + r0 + r;
    Pbo[(size_t)n * 160 + w * 32 + oo] = f2b(d0[r]) | ((unsigned)f2b(d2[r]) << 16);
    Pbo[(size_t)n * 160 + w * 32 + 16 + oo] = f2b(d1[r]) | ((unsigned)f2b(d3[r]) << 16);
    if (w == 0) Pbo[(size_t)n * 160 + 128 + oo] = f2b(d4[r]);
    else if (w == 1) Pbo[(size_t)n * 160 + 128 + 16 + oo] = f2b(d4[r]);
    else if (w == 2) Pro[(size_t)n * 32 + oo] = d4[r];
    else Pro[(size_t)n * 32 + 16 + oo] = d4[r];
  }
}

// ---------- final: aggregate -> h -> fc2 -> out (1 wave/node) ----------
__global__ void k_final(const int* __restrict__ rowstart, const int* __restrict__ cnt,
                        const float* __restrict__ icnt, const int* __restrict__ srcs,
                        const float* __restrict__ kcs, const unsigned* __restrict__ Pb,
                        const float* __restrict__ Pr, const float* __restrict__ cbias,
                        const float* __restrict__ fc2w, const float* __restrict__ fc2b,
                        float* __restrict__ out) {
  int t = blockIdx.x * TPB + threadIdx.x;
  int n = t >> 6;
  if (n >= NN) return;
  int lane = threadIdx.x & 63;
  int half = lane >> 5, o = lane & 31;
  int rs = rowstart[n], re = rs + cnt[n];
  float acc = 0.f;
  for (int j = rs + half; j < re; j += 2) {
    int s = srcs[j];
    float ckv = (o < 8) ? kcs[(size_t)j * 8 + o] : 0.f;
    const unsigned* Ps = Pb + (size_t)s * 160;
    unsigned w0 = Ps[o], w1 = Ps[32 + o], w2 = Ps[64 + o], w3 = Ps[96 + o];
    unsigned wb = Ps[128 + o];
    acc += blo(wb);
    acc = fmaf(__shfl(ckv, 0, 32), blo(w0), acc);
    acc = fmaf(__shfl(ckv, 1, 32), bhi(w0), acc);
    acc = fmaf(__shfl(ckv, 2, 32), blo(w1), acc);
    acc = fmaf(__shfl(ckv, 3, 32), bhi(w1), acc);
    acc = fmaf(__shfl(ckv, 4, 32), blo(w2), acc);
    acc = fmaf(__shfl(ckv, 5, 32), bhi(w2), acc);
    acc = fmaf(__shfl(ckv, 6, 32), blo(w3), acc);
    acc = fmaf(__shfl(ckv, 7, 32), bhi(w3), acc);
  }
  acc += __shfl_xor(acc, 32, 64);
  float hv = fmaxf(fmaf(acc, icnt[n], Pr[(size_t)n * 32 + o] + cbias[o]), 0.f);
  float s2 = hv * fc2w[o];
#pragma unroll
  for (int d = 16; d; d >>= 1) s2 += __shfl_xor(s2, d, 32);
  if (lane == 0) out[n] = s2 + fc2b[0];
}

extern "C" void kernel_launch(void* const* d_in, const int* in_sizes, int n_in,
                              void* d_out, int out_size, void* d_ws, size_t ws_size,
                              hipStream_t stream) {
  const float* x     = (const float*)d_in[0];
  const int*   ei    = (const int*)d_in[1];
  const float* ea    = (const float*)d_in[2];
  const float* fc1w  = (const float*)d_in[3];
  const float* fc1b  = (const float*)d_in[4];
  const float* kw1   = (const float*)d_in[5];
  const float* kb1   = (const float*)d_in[6];
  const float* kw2   = (const float*)d_in[7];
  const float* kb2   = (const float*)d_in[8];
  const float* root  = (const float*)d_in[9];
  const float* cbias = (const float*)d_in[10];
  const float* fc2w  = (const float*)d_in[11];
  const float* fc2b  = (const float*)d_in[12];
  float* out = (float*)d_out;
  const int* srcp = ei;
  const int* dstp = ei + NE;

  float* ws = (float*)d_ws;
  float* kc       = ws;                        // NE*8
  float* kcs      = kc + NE * 8;               // NE*8
  int*   srcs     = (int*)(kcs + NE * 8);      // NE
  float* icnt     = (float*)(srcs + NE);       // NN
  float* Pr0      = icnt + NN;                 // NN*32
  float* Pr1      = Pr0 + NN * 32;             // NN*32
  int*   cnt      = (int*)(Pr1 + NN * 32);     // NN
  int*   rowstart = cnt + NN;                  // NN
  int*   wpos     = rowstart + NN;             // NN
  int*   gtotal   = wpos + NN;                 // 1 (+pad)
  uint4* Wb       = (uint4*)(gtotal + 128);    // 1280 uint4
  unsigned* Pb0   = (unsigned*)(Wb + 1280);    // NN*160
  unsigned* Pb1   = Pb0 + (size_t)NN * 160;    // NN*160

  k_init<<<SB + 5, TPB, 0, stream>>>(cnt, gtotal, kw2, kb2, root, Wb);
  k_prep<<<(NE + TPB - 1) / TPB, TPB, 0, stream>>>(ea, kw1, kb1, dstp, kc, cnt);
  k_alloc<<<SB, TPB, 0, stream>>>(cnt, gtotal, rowstart, wpos, icnt);
  k_scatnode<<<NB1 + NB1, TPB, 0, stream>>>(dstp, srcp, kc, wpos, srcs, kcs,
                                            x, fc1w, fc1b, Wb, Pb0, Pr0);
  k_fused<<<NW, TPB, 0, stream>>>(rowstart, cnt, icnt, srcs, kcs, Pb0, Pr0, cbias,
                                  Wb, Pb1, Pr1);
  k_fused<<<NW, TPB, 0, stream>>>(rowstart, cnt, icnt, srcs, kcs, Pb1, Pr1, cbias,
                                  Wb, Pb0, Pr0);
  k_fused<<<NW, TPB, 0, stream>>>(rowstart, cnt, icnt, srcs, kcs, Pb0, Pr0, cbias,
                                  Wb, Pb1, Pr1);
  k_final<<<(NN * 64 + TPB - 1) / TPB, TPB, 0, stream>>>(
      rowstart, cnt, icnt, srcs, kcs, Pb1, Pr1, cbias, fc2w, fc2b, out);
}

// Round 17
// 114.291 us; speedup vs baseline: 3.3966x; 1.0449x over previous
//
#include <hip/hip_runtime.h>

#define NN 30000
#define NE 120000
#define TPB 256
#define SB 118   // ceil(NN/256)
#define NW 1875  // NN/16 exact
#define NB1 469  // ceil(NW*64/256) blocks for node1 part

typedef __attribute__((ext_vector_type(8))) __bf16 bf16x8;
typedef __attribute__((ext_vector_type(4))) float f32x4;

union B8 { bf16x8 b; unsigned short u[8]; uint4 q; };

__device__ __forceinline__ float blo(unsigned u) { return __uint_as_float(u << 16); }
__device__ __forceinline__ float bhi(unsigned u) { return __uint_as_float(u & 0xffff0000u); }

__device__ __forceinline__ unsigned short f2b(float f) {
  unsigned u = __float_as_uint(f);
  return (unsigned short)((u + 0x7fff + ((u >> 16) & 1)) >> 16);  // RNE
}

// ---------- weight fragment packing ----------
__device__ __forceinline__ void pack_wb(int f, const float* kw2, const float* kb2,
                                        const float* root, uint4* Wb) {
  int ct = f >> 6, l = f & 63;
  int j = ct * 16 + (l & 15);
  int k = j >> 5, o = j & 31;
  int i0 = (l >> 4) * 8;
  B8 w;
#pragma unroll
  for (int ii = 0; ii < 8; ii++) {
    int i = i0 + ii;
    float v;
    if (k < 8) v = kw2[k * 1024 + i * 32 + o];
    else if (k == 8) v = kb2[i * 32 + o];
    else v = root[i * 32 + o];
    w.u[ii] = f2b(v);
  }
  Wb[f] = w.q;
}

__global__ void k_init(int* __restrict__ cnt, int* __restrict__ gtotal,
                       const float* __restrict__ kw2, const float* __restrict__ kb2,
                       const float* __restrict__ root, uint4* __restrict__ Wb) {
  int bid = blockIdx.x;
  if (bid < SB) {
    int n = bid * TPB + threadIdx.x;
    if (n < NN) cnt[n] = 0;
    if (bid == 0 && threadIdx.x == 0) *gtotal = 0;
  } else {
    int f = (bid - SB) * TPB + threadIdx.x;
    if (f < 1280) pack_wb(f, kw2, kb2, root, Wb);
  }
}

__global__ void k_prep(const float* __restrict__ ea, const float* __restrict__ w1,
                       const float* __restrict__ b1, const int* __restrict__ dst,
                       float* __restrict__ kc, int* __restrict__ cnt) {
  int e = blockIdx.x * TPB + threadIdx.x;
  if (e >= NE) return;
  float a[6];
#pragma unroll
  for (int i = 0; i < 6; i++) a[i] = ea[e * 6 + i];
#pragma unroll
  for (int k = 0; k < 8; k++) {
    float s = b1[k];
#pragma unroll
    for (int i = 0; i < 6; i++) s = fmaf(a[i], w1[i * 8 + k], s);
    kc[e * 8 + k] = fmaxf(s, 0.f);
  }
  atomicAdd(&cnt[dst[e]], 1);
}

// CSR range allocation without prefix scan (inter-node order irrelevant)
__global__ void k_alloc(const int* __restrict__ cnt, int* __restrict__ gtotal,
                        int* __restrict__ rowstart, int* __restrict__ wpos,
                        float* __restrict__ icnt) {
  int n = blockIdx.x * TPB + threadIdx.x;
  if (n >= NN) return;
  int c = cnt[n];
  int r = atomicAdd(gtotal, c);
  rowstart[n] = r;
  wpos[n] = r;
  icnt[n] = 1.f / (float)max(c, 1);
}

// fused: blocks [0,NB1) = first MFMA transform (h0=fc1(x)); blocks [NB1,..) = scatter
__global__ __launch_bounds__(TPB, 4) void k_scatnode(
    const int* __restrict__ dst, const int* __restrict__ src,
    const float* __restrict__ kc, int* __restrict__ wpos, int* __restrict__ srcs,
    float* __restrict__ kcs, const float* __restrict__ x,
    const float* __restrict__ fc1w, const float* __restrict__ fc1b,
    const uint4* __restrict__ Wb, unsigned* __restrict__ Pb, float* __restrict__ Pr) {
  if (blockIdx.x < NB1) {
    const int l = threadIdx.x & 63;
    const int wid = blockIdx.x * (TPB / 64) + (threadIdx.x >> 6);
    if (wid >= NW) return;
    const int nb = wid * 16;
    B8 Bf[20];
#pragma unroll
    for (int ct = 0; ct < 20; ct++) Bf[ct].q = Wb[ct * 64 + l];
    const int row = nb + (l & 15);
    const int k0 = (l >> 4) * 8;
    B8 af;
    float xv = x[row];
#pragma unroll
    for (int ii = 0; ii < 8; ii++)
      af.u[ii] = f2b(fmaf(xv, fc1w[k0 + ii], fc1b[k0 + ii]));
    const int oo = l & 15;
    const int r0 = (l >> 4) * 4;
#pragma unroll
    for (int kp = 0; kp < 4; kp++) {
      f32x4 d0 = {0.f, 0.f, 0.f, 0.f}, d1 = d0, d2 = d0, d3 = d0;
      d0 = __builtin_amdgcn_mfma_f32_16x16x32_bf16(af.b, Bf[4 * kp + 0].b, d0, 0, 0, 0);
      d1 = __builtin_amdgcn_mfma_f32_16x16x32_bf16(af.b, Bf[4 * kp + 1].b, d1, 0, 0, 0);
      d2 = __builtin_amdgcn_mfma_f32_16x16x32_bf16(af.b, Bf[4 * kp + 2].b, d2, 0, 0, 0);
      d3 = __builtin_amdgcn_mfma_f32_16x16x32_bf16(af.b, Bf[4 * kp + 3].b, d3, 0, 0, 0);
#pragma unroll
      for (int r = 0; r < 4; r++) {
        int n = nb + r0 + r;
        Pb[(size_t)n * 160 + kp * 32 + oo] = f2b(d0[r]) | ((unsigned)f2b(d2[r]) << 16);
        Pb[(size_t)n * 160 + kp * 32 + 16 + oo] = f2b(d1[r]) | ((unsigned)f2b(d3[r]) << 16);
      }
    }
    {
      f32x4 d0 = {0.f, 0.f, 0.f, 0.f}, d1 = d0, d2 = d0, d3 = d0;
      d0 = __builtin_amdgcn_mfma_f32_16x16x32_bf16(af.b, Bf[16].b, d0, 0, 0, 0);
      d1 = __builtin_amdgcn_mfma_f32_16x16x32_bf16(af.b, Bf[17].b, d1, 0, 0, 0);
      d2 = __builtin_amdgcn_mfma_f32_16x16x32_bf16(af.b, Bf[18].b, d2, 0, 0, 0);
      d3 = __builtin_amdgcn_mfma_f32_16x16x32_bf16(af.b, Bf[19].b, d3, 0, 0, 0);
#pragma unroll
      for (int r = 0; r < 4; r++) {
        int n = nb + r0 + r;
        Pb[(size_t)n * 160 + 128 + oo] = f2b(d0[r]);
        Pb[(size_t)n * 160 + 128 + 16 + oo] = f2b(d1[r]);
        Pr[(size_t)n * 32 + oo] = d2[r];
        Pr[(size_t)n * 32 + 16 + oo] = d3[r];
      }
    }
  } else {
    int e = (blockIdx.x - NB1) * TPB + threadIdx.x;
    if (e >= NE) return;
    int pos = atomicAdd(&wpos[dst[e]], 1);
    srcs[pos] = src[e];
    float4 a = *(const float4*)&kc[e * 8];
    float4 b = *(const float4*)&kc[e * 8 + 4];
    *(float4*)&kcs[(size_t)pos * 8] = a;
    *(float4*)&kcs[(size_t)pos * 8 + 4] = b;
  }
}

// 4-edges-in-flight gather for one node; lane = eq*16+o16; returns acc for
// outputs o16 (acc0) and o16+16 (acc1), valid in all lanes after xor-merge.
__device__ __forceinline__ void gather4(
    int rs, int re, int eq, int o16, const int* __restrict__ srcs,
    const float* __restrict__ kcs, const unsigned* __restrict__ Pb,
    float& acc0, float& acc1) {
  acc0 = 0.f; acc1 = 0.f;
  for (int j0 = rs; j0 < re; j0 += 4) {
    int j = j0 + eq;
    bool valid = (j < re);
    int jj = valid ? j : rs;
    int s = srcs[jj];
    float ckv = (o16 < 8) ? kcs[(size_t)jj * 8 + o16] : 0.f;
    const unsigned* Ps = Pb + (size_t)s * 160;
    unsigned pa0 = Ps[o16],       pa1 = Ps[16 + o16];
    unsigned pb0 = Ps[32 + o16],  pb1 = Ps[48 + o16];
    unsigned pc0 = Ps[64 + o16],  pc1 = Ps[80 + o16];
    unsigned pd0 = Ps[96 + o16],  pd1 = Ps[112 + o16];
    unsigned pe0 = Ps[128 + o16], pe1 = Ps[144 + o16];
    float m0 = blo(pe0), m1 = blo(pe1);  // bias row, coefficient 1
    float c0 = __shfl(ckv, 0, 16), c1 = __shfl(ckv, 1, 16);
    float c2 = __shfl(ckv, 2, 16), c3 = __shfl(ckv, 3, 16);
    float c4 = __shfl(ckv, 4, 16), c5 = __shfl(ckv, 5, 16);
    float c6 = __shfl(ckv, 6, 16), c7 = __shfl(ckv, 7, 16);
    m0 = fmaf(c0, blo(pa0), m0); m1 = fmaf(c0, blo(pa1), m1);
    m0 = fmaf(c1, bhi(pa0), m0); m1 = fmaf(c1, bhi(pa1), m1);
    m0 = fmaf(c2, blo(pb0), m0); m1 = fmaf(c2, blo(pb1), m1);
    m0 = fmaf(c3, bhi(pb0), m0); m1 = fmaf(c3, bhi(pb1), m1);
    m0 = fmaf(c4, blo(pc0), m0); m1 = fmaf(c4, blo(pc1), m1);
    m0 = fmaf(c5, bhi(pc0), m0); m1 = fmaf(c5, bhi(pc1), m1);
    m0 = fmaf(c6, blo(pd0), m0); m1 = fmaf(c6, blo(pd1), m1);
    m0 = fmaf(c7, bhi(pd0), m0); m1 = fmaf(c7, bhi(pd1), m1);
    if (valid) { acc0 += m0; acc1 += m1; }
  }
  acc0 += __shfl_xor(acc0, 16, 64);
  acc0 += __shfl_xor(acc0, 32, 64);
  acc1 += __shfl_xor(acc1, 16, 64);
  acc1 += __shfl_xor(acc1, 32, 64);
}

// ---------- fused layer: 4-edge gather (4 waves x 4 nodes) -> hL -> MFMA ----------
__global__ __launch_bounds__(TPB, 4) void k_fused(
    const int* __restrict__ rowstart, const int* __restrict__ cnt,
    const float* __restrict__ icnt, const int* __restrict__ srcs,
    const float* __restrict__ kcs, const unsigned* __restrict__ Pbi,
    const float* __restrict__ Pri, const float* __restrict__ cbias,
    const uint4* __restrict__ Wb, unsigned* __restrict__ Pbo,
    float* __restrict__ Pro) {
  __shared__ float hL[512];
  const int tid = threadIdx.x, w = tid >> 6, lane = tid & 63;
  const int nb = blockIdx.x * 16;
  const int eq = lane >> 4, o16 = lane & 15;
#pragma unroll 1
  for (int q = 0; q < 4; q++) {
    int n = nb + 4 * w + q;
    int rs = rowstart[n], re = rs + cnt[n];
    float acc0, acc1;
    gather4(rs, re, eq, o16, srcs, kcs, Pbi, acc0, acc1);
    if (lane < 16) {
      float ic = icnt[n];
      int nq = 4 * w + q;
      hL[nq * 32 + o16] =
          fmaxf(fmaf(acc0, ic, Pri[(size_t)n * 32 + o16] + cbias[o16]), 0.f);
      hL[nq * 32 + 16 + o16] =
          fmaxf(fmaf(acc1, ic, Pri[(size_t)n * 32 + 16 + o16] + cbias[16 + o16]), 0.f);
    }
  }
  __syncthreads();
  // transform (R14/R15-proven): wave w owns kp=w + ct 16+w
  B8 Bf0, Bf1, Bf2, Bf3, Bf4;
  Bf0.q = Wb[(4 * w + 0) * 64 + lane];
  Bf1.q = Wb[(4 * w + 1) * 64 + lane];
  Bf2.q = Wb[(4 * w + 2) * 64 + lane];
  Bf3.q = Wb[(4 * w + 3) * 64 + lane];
  Bf4.q = Wb[(16 + w) * 64 + lane];
  const int row = lane & 15, k0 = (lane >> 4) * 8;
  B8 af;
#pragma unroll
  for (int ii = 0; ii < 8; ii++) af.u[ii] = f2b(hL[row * 32 + k0 + ii]);
  f32x4 z = {0.f, 0.f, 0.f, 0.f};
  f32x4 d0 = __builtin_amdgcn_mfma_f32_16x16x32_bf16(af.b, Bf0.b, z, 0, 0, 0);
  f32x4 d1 = __builtin_amdgcn_mfma_f32_16x16x32_bf16(af.b, Bf1.b, z, 0, 0, 0);
  f32x4 d2 = __builtin_amdgcn_mfma_f32_16x16x32_bf16(af.b, Bf2.b, z, 0, 0, 0);
  f32x4 d3 = __builtin_amdgcn_mfma_f32_16x16x32_bf16(af.b, Bf3.b, z, 0, 0, 0);
  f32x4 d4 = __builtin_amdgcn_mfma_f32_16x16x32_bf16(af.b, Bf4.b, z, 0, 0, 0);
  const int oo = lane & 15, r0 = (lane >> 4) * 4;
#pragma unroll
  for (int r = 0; r < 4; r++) {
    int n = nb + r0 + r;
    Pbo[(size_t)n * 160 + w * 32 + oo] = f2b(d0[r]) | ((unsigned)f2b(d2[r]) << 16);
    Pbo[(size_t)n * 160 + w * 32 + 16 + oo] = f2b(d1[r]) | ((unsigned)f2b(d3[r]) << 16);
    if (w == 0) Pbo[(size_t)n * 160 + 128 + oo] = f2b(d4[r]);
    else if (w == 1) Pbo[(size_t)n * 160 + 128 + 16 + oo] = f2b(d4[r]);
    else if (w == 2) Pro[(size_t)n * 32 + oo] = d4[r];
    else Pro[(size_t)n * 32 + 16 + oo] = d4[r];
  }
}

// ---------- final: 4-edge gather -> h -> fc2 -> out (1 wave/node) ----------
__global__ void k_final(const int* __restrict__ rowstart, const int* __restrict__ cnt,
                        const float* __restrict__ icnt, const int* __restrict__ srcs,
                        const float* __restrict__ kcs, const unsigned* __restrict__ Pb,
                        const float* __restrict__ Pr, const float* __restrict__ cbias,
                        const float* __restrict__ fc2w, const float* __restrict__ fc2b,
                        float* __restrict__ out) {
  int t = blockIdx.x * TPB + threadIdx.x;
  int n = t >> 6;
  if (n >= NN) return;
  int lane = threadIdx.x & 63;
  int eq = lane >> 4, o16 = lane & 15;
  int rs = rowstart[n], re = rs + cnt[n];
  float acc0, acc1;
  gather4(rs, re, eq, o16, srcs, kcs, Pb, acc0, acc1);
  float ic = icnt[n];
  float hv0 = fmaxf(fmaf(acc0, ic, Pr[(size_t)n * 32 + o16] + cbias[o16]), 0.f);
  float hv1 = fmaxf(fmaf(acc1, ic, Pr[(size_t)n * 32 + 16 + o16] + cbias[16 + o16]), 0.f);
  float s2 = fmaf(hv0, fc2w[o16], hv1 * fc2w[16 + o16]);
#pragma unroll
  for (int d = 8; d; d >>= 1) s2 += __shfl_xor(s2, d, 16);
  if (lane == 0) out[n] = s2 + fc2b[0];
}

extern "C" void kernel_launch(void* const* d_in, const int* in_sizes, int n_in,
                              void* d_out, int out_size, void* d_ws, size_t ws_size,
                              hipStream_t stream) {
  const float* x     = (const float*)d_in[0];
  const int*   ei    = (const int*)d_in[1];
  const float* ea    = (const float*)d_in[2];
  const float* fc1w  = (const float*)d_in[3];
  const float* fc1b  = (const float*)d_in[4];
  const float* kw1   = (const float*)d_in[5];
  const float* kb1   = (const float*)d_in[6];
  const float* kw2   = (const float*)d_in[7];
  const float* kb2   = (const float*)d_in[8];
  const float* root  = (const float*)d_in[9];
  const float* cbias = (const float*)d_in[10];
  const float* fc2w  = (const float*)d_in[11];
  const float* fc2b  = (const float*)d_in[12];
  float* out = (float*)d_out;
  const int* srcp = ei;
  const int* dstp = ei + NE;

  float* ws = (float*)d_ws;
  float* kc       = ws;                        // NE*8
  float* kcs      = kc + NE * 8;               // NE*8
  int*   srcs     = (int*)(kcs + NE * 8);      // NE
  float* icnt     = (float*)(srcs + NE);       // NN
  float* Pr0      = icnt + NN;                 // NN*32
  float* Pr1      = Pr0 + NN * 32;             // NN*32
  int*   cnt      = (int*)(Pr1 + NN * 32);     // NN
  int*   rowstart = cnt + NN;                  // NN
  int*   wpos     = rowstart + NN;             // NN
  int*   gtotal   = wpos + NN;                 // 1 (+pad)
  uint4* Wb       = (uint4*)(gtotal + 128);    // 1280 uint4
  unsigned* Pb0   = (unsigned*)(Wb + 1280);    // NN*160
  unsigned* Pb1   = Pb0 + (size_t)NN * 160;    // NN*160

  k_init<<<SB + 5, TPB, 0, stream>>>(cnt, gtotal, kw2, kb2, root, Wb);
  k_prep<<<(NE + TPB - 1) / TPB, TPB, 0, stream>>>(ea, kw1, kb1, dstp, kc, cnt);
  k_alloc<<<SB, TPB, 0, stream>>>(cnt, gtotal, rowstart, wpos, icnt);
  k_scatnode<<<NB1 + NB1, TPB, 0, stream>>>(dstp, srcp, kc, wpos, srcs, kcs,
                                            x, fc1w, fc1b, Wb, Pb0, Pr0);
  k_fused<<<NW, TPB, 0, stream>>>(rowstart, cnt, icnt, srcs, kcs, Pb0, Pr0, cbias,
                                  Wb, Pb1, Pr1);
  k_fused<<<NW, TPB, 0, stream>>>(rowstart, cnt, icnt, srcs, kcs, Pb1, Pr1, cbias,
                                  Wb, Pb0, Pr0);
  k_fused<<<NW, TPB, 0, stream>>>(rowstart, cnt, icnt, srcs, kcs, Pb0, Pr0, cbias,
                                  Wb, Pb1, Pr1);
  k_final<<<(NN * 64 + TPB - 1) / TPB, TPB, 0, stream>>>(
      rowstart, cnt, icnt, srcs, kcs, Pb1, Pr1, cbias, fc2w, fc2b, out);
}